// Round 4
// baseline (177.258 us; speedup 1.0000x reference)
//
#include <hip/hip_runtime.h>

// B=2, N=96, D=64, H=4, DK=16
#define ELEM_B 589824    // 9216*64 floats per batch per tensor
#define TENS   1179648   // 2*ELEM_B floats per projected tensor
#define T_ROWS 18432     // total rows

// ---------------------------------------------------------------------------
// 32-row x 64-col projection tile (proven R2 version): dst = src @ W^T + b.
// 256 threads: c = t&63, rg = t>>6 owns 8 rows. W staged pitch-68.
// ---------------------------------------------------------------------------
__device__ __forceinline__ void proj_tile(
    const float* __restrict__ src, const float* __restrict__ w,
    const float* __restrict__ bias, float* __restrict__ dst,
    int row0, int t, float* sw, float* srow, float* sb)
{
#pragma unroll
    for (int j = 0; j < 4; ++j) {           // 1024 float4 slots of W
        const int s = t + j * 256;
        const int c = s >> 4, k4 = s & 15;
        *(float4*)&sw[c * 68 + k4 * 4] = *(const float4*)(w + s * 4);
    }
#pragma unroll
    for (int j = 0; j < 2; ++j) {           // 512 float4 slots of src rows
        const int s = t + j * 256;
        *(float4*)&srow[s * 4] = *(const float4*)(src + row0 * 64 + s * 4);
    }
    if (t < 64) sb[t] = bias[t];
    __syncthreads();

    const int c = t & 63, rg = t >> 6;
    float acc[8];
#pragma unroll
    for (int r = 0; r < 8; ++r) acc[r] = sb[c];
#pragma unroll
    for (int k4 = 0; k4 < 16; ++k4) {
        const float4 w4 = *(const float4*)&sw[c * 68 + k4 * 4];
#pragma unroll
        for (int r = 0; r < 8; ++r) {
            const float4 s4 = *(const float4*)&srow[(rg * 8 + r) * 64 + k4 * 4];
            acc[r] = fmaf(s4.x, w4.x, acc[r]);
            acc[r] = fmaf(s4.y, w4.y, acc[r]);
            acc[r] = fmaf(s4.z, w4.z, acc[r]);
            acc[r] = fmaf(s4.w, w4.w, acc[r]);
        }
    }
#pragma unroll
    for (int r = 0; r < 8; ++r)
        dst[(row0 + rg * 8 + r) * 64 + c] = acc[r];
}

__global__ __launch_bounds__(256) void proj4_kernel(
    const float* __restrict__ state,
    const float* __restrict__ w0, const float* __restrict__ b0,
    const float* __restrict__ w1, const float* __restrict__ b1,
    const float* __restrict__ w2, const float* __restrict__ b2,
    const float* __restrict__ w3, const float* __restrict__ b3,
    float* __restrict__ o0, float* __restrict__ o1,
    float* __restrict__ o2, float* __restrict__ o3)
{
    __shared__ float sw[64 * 68];
    __shared__ float srow[32 * 64];
    __shared__ float sb[64];
    const int mat  = blockIdx.x & 3;
    const int row0 = (blockIdx.x >> 2) * 32;
    const float* w = (mat == 0) ? w0 : (mat == 1) ? w1 : (mat == 2) ? w2 : w3;
    const float* b = (mat == 0) ? b0 : (mat == 1) ? b1 : (mat == 2) ? b2 : b3;
    float* o       = (mat == 0) ? o0 : (mat == 1) ? o1 : (mat == 2) ? o2 : o3;
    proj_tile(state, w, b, o, row0, threadIdx.x, sw, srow, sb);
}

__global__ __launch_bounds__(256) void proj1_kernel(
    const float* __restrict__ src, const float* __restrict__ w,
    const float* __restrict__ b, float* __restrict__ dst)
{
    __shared__ float sw[64 * 68];
    __shared__ float srow[32 * 64];
    __shared__ float sb[64];
    proj_tile(src, w, b, dst, blockIdx.x * 32, threadIdx.x, sw, srow, sb);
}

// ---------------------------------------------------------------------------
// Fused single-pass edge attention (no P materialization, no LDS, no barrier).
// Block = 1 wave (64 threads) = (y 0..15, dq 0..3); covers (bh, 4 x's, 16 y's).
// Grid = 8 bh x 24 xt x 6 yt = 1152 blocks.
// Per a: lanes compute partial dot4 for each xi, quad-butterfly sum -> full
// dot16; lane exps xi==dq only; 3 shfls share p across quad; register accum
// acc[j] for xi = dq^j. O = acc/den at the end (single-pass softmax, no max:
// |S| << 1 by construction).
// ---------------------------------------------------------------------------
__global__ __launch_bounds__(64) void fused_attn_kernel(
    const float* __restrict__ lk, const float* __restrict__ rk,
    const float* __restrict__ lv, const float* __restrict__ rv,
    float* __restrict__ xb)
{
    const int bid = blockIdx.x;
    const int yt = bid % 6;
    const int xt = (bid / 6) % 24;
    const int bh = bid / 144;
    const int b = bh >> 2, h = bh & 3;
    const int x0 = xt * 4, y0 = yt * 16;
    const int t = threadIdx.x;
    const int y = t >> 2, dq = t & 3;
    const int base = b * ELEM_B + h * 16;

    // row pointers (advance by a*6144 floats for rk/rv; a*64 for lk/lv)
    const float* rkp = rk + base + (y0 + y) * 64 + dq * 4;
    const float* rvp = rv + base + (y0 + y) * 64 + dq * 4;
    const float* lkp[4];
    const float* lvp[4];
#pragma unroll
    for (int xi = 0; xi < 4; ++xi)
        lkp[xi] = lk + base + (size_t)(x0 + xi) * 96 * 64 + dq * 4;
#pragma unroll
    for (int j = 0; j < 4; ++j)
        lvp[j] = lv + base + (size_t)(x0 + (dq ^ j)) * 96 * 64 + dq * 4;

    float4 acc[4];
    float den[4];
#pragma unroll
    for (int j = 0; j < 4; ++j) {
        acc[j] = make_float4(0.f, 0.f, 0.f, 0.f);
        den[j] = 0.f;
    }

#pragma unroll 2
    for (int a = 0; a < 96; ++a) {
        const float4 rk4 = *(const float4*)(rkp + (size_t)a * 6144);
        const float4 rv4 = *(const float4*)(rvp + (size_t)a * 6144);

        // full dot16 for each xi via quad butterfly over partial dot4s
        float s[4];
#pragma unroll
        for (int xi = 0; xi < 4; ++xi) {
            const float4 l4 = *(const float4*)(lkp[xi] + a * 64);
            float par = l4.x * rk4.x;
            par = fmaf(l4.y, rk4.y, par);
            par = fmaf(l4.z, rk4.z, par);
            par = fmaf(l4.w, rk4.w, par);
            float v = par + __shfl_xor(par, 1);
            s[xi] = v + __shfl_xor(v, 2);
        }
        // lane exps only xi == dq, then distributes across the quad
        const float sown = (dq == 0) ? s[0] : (dq == 1) ? s[1] : (dq == 2) ? s[2] : s[3];
        const float pown = __expf(sown * 0.25f);       // 1/sqrt(16)
        const float p1 = __shfl_xor(pown, 1);          // xi = dq^1
        const float p2 = __shfl_xor(pown, 2);          // xi = dq^2
        const float p3 = __shfl_xor(p1, 2);            // xi = dq^3
        const float pj[4] = {pown, p1, p2, p3};

#pragma unroll
        for (int j = 0; j < 4; ++j) {
            const float p = pj[j];
            const float4 l4 = *(const float4*)(lvp[j] + a * 64);
            den[j] += p;
            acc[j].x = fmaf(p * l4.x, rv4.x, acc[j].x);
            acc[j].y = fmaf(p * l4.y, rv4.y, acc[j].y);
            acc[j].z = fmaf(p * l4.z, rv4.z, acc[j].z);
            acc[j].w = fmaf(p * l4.w, rv4.w, acc[j].w);
        }
    }

#pragma unroll
    for (int j = 0; j < 4; ++j) {
        const int xi = dq ^ j;
        const float inv = 1.0f / den[j];
        float4 o;
        o.x = acc[j].x * inv; o.y = acc[j].y * inv;
        o.z = acc[j].z * inv; o.w = acc[j].w * inv;
        *(float4*)(xb + base + (size_t)((x0 + xi) * 96 + y0 + y) * 64 + dq * 4) = o;
    }
}

extern "C" void kernel_launch(void* const* d_in, const int* in_sizes, int n_in,
                              void* d_out, int out_size, void* d_ws, size_t ws_size,
                              hipStream_t stream)
{
    const float* state = (const float*)d_in[0];
    const float* w_lk  = (const float*)d_in[1];
    const float* b_lk  = (const float*)d_in[2];
    const float* w_rk  = (const float*)d_in[3];
    const float* b_rk  = (const float*)d_in[4];
    const float* w_lv  = (const float*)d_in[5];
    const float* b_lv  = (const float*)d_in[6];
    const float* w_rv  = (const float*)d_in[7];
    const float* b_rv  = (const float*)d_in[8];
    const float* w_out = (const float*)d_in[9];
    const float* b_out = (const float*)d_in[10];
    float* out = (float*)d_out;

    float* ws = (float*)d_ws;
    float* lk = ws;
    float* rk = ws + (size_t)TENS;
    float* lv = ws + (size_t)2 * TENS;
    float* rv = ws + (size_t)3 * TENS;
    float* xb = ws + (size_t)4 * TENS;

    proj4_kernel<<<4 * (T_ROWS / 32), 256, 0, stream>>>(
        state, w_lk, b_lk, w_rk, b_rk, w_lv, b_lv, w_rv, b_rv, lk, rk, lv, rv);
    fused_attn_kernel<<<1152, 64, 0, stream>>>(lk, rk, lv, rv, xb);
    proj1_kernel<<<T_ROWS / 32, 256, 0, stream>>>(xb, w_out, b_out, out);
}